// Round 7
// baseline (16.828 us; speedup 1.0000x reference)
//
#include <hip/hip_runtime.h>
#include <math.h>

#define M_SAMPLES 131072
#define BLK 64
#define NBLK (M_SAMPLES / BLK)   // 2048
#define BLKF 256

__device__ __forceinline__ float logaddexp_f(float a, float b) {
    float m = fmaxf(a, b);
    float d = fminf(a, b) - m;
    return m + __logf(1.f + __expf(d));
}

// C(m,k) table (rodata; runtime-indexed loads are memory, not registers)
__device__ const float BINOM[8][8] = {
  {1,0,0,0,0,0,0,0},{1,1,0,0,0,0,0,0},{1,2,1,0,0,0,0,0},{1,3,3,1,0,0,0,0},
  {1,4,6,4,1,0,0,0},{1,5,10,10,5,1,0,0},{1,6,15,20,15,6,1,0},{1,7,21,35,35,21,7,1}};

__global__ __launch_bounds__(BLK, 2) void bez_main_kernel(
    const float* __restrict__ P0, const float* __restrict__ Pd,
    const float* __restrict__ Pmid, const float* __restrict__ ts,
    float* __restrict__ partial)
{
    __shared__ float sP[8][8][2];
    __shared__ float2 sA2[8][8];    // monomial coeffs: T_j(t) = sum_m A[m][j] t^m
    __shared__ float sSP2[13];      // |T'|^2 summed over j: real poly deg 12
    __shared__ float sAC2[11];      // |T''|^2 summed over j: real poly deg 10

    const int tid = threadIdx.x;
    const int gid = blockIdx.x * BLK + tid;
    const float t = ts[gid];

    if (tid < 16) { sP[0][tid >> 1][tid & 1] = P0[tid]; sP[7][tid >> 1][tid & 1] = Pd[tid]; }
    for (int e = tid; e < 96; e += BLK) {
        int r = e / 16, rem = e % 16;
        sP[1 + r][rem >> 1][rem & 1] = Pmid[e];
    }
    __syncthreads();
    // Bezier -> monomial: A_m = C(7,m) * sum_{k<=m} (-1)^(m-k) C(m,k) P_k
    {
        int m = tid >> 3, j = tid & 7;
        float aR = 0.f, aI = 0.f;
        float sgn = (m & 1) ? -1.f : 1.f;           // (-1)^m at k=0
        for (int k = 0; k <= m; ++k) {
            aR += sgn * BINOM[m][k] * sP[k][j][0];
            aI += sgn * BINOM[m][k] * sP[k][j][1];
            sgn = -sgn;
        }
        sA2[m][j] = make_float2(BINOM[7][m] * aR, BINOM[7][m] * aI);
    }
    __syncthreads();
    // Block-level: coefficients of sum_j |T'_j|^2 (deg 12) and sum_j |T''_j|^2 (deg 10).
    if (tid < 13) {
        int d = tid; float s = 0.f;
        int lo = d > 6 ? d - 6 : 0, hi = d < 6 ? d : 6;
        for (int m = lo; m <= hi; ++m) {
            int mp = d - m;
            float wgt = (float)((m + 1) * (mp + 1));
            for (int j = 0; j < 8; ++j) {
                float2 a = sA2[m + 1][j], b = sA2[mp + 1][j];
                s += wgt * (a.x * b.x + a.y * b.y);
            }
        }
        sSP2[d] = s;
    } else if (tid < 24) {
        int d = tid - 13; float s = 0.f;
        int lo = d > 5 ? d - 5 : 0, hi = d < 5 ? d : 5;
        for (int m = lo; m <= hi; ++m) {
            int mp = d - m;
            float wgt = (float)((m + 2) * (m + 1) * (mp + 2) * (mp + 1));
            for (int j = 0; j < 8; ++j) {
                float2 a = sA2[m + 2][j], b = sA2[mp + 2][j];
                s += wgt * (a.x * b.x + a.y * b.y);
            }
        }
        sAC2[d] = s;
    }
    __syncthreads();

    // Per-thread: T_j via Horner (ascending storage f[7-j] = T_j), monic f_8 = 1.
    float fr[9], fi[9];
#pragma unroll
    for (int j = 0; j < 8; ++j) {
        float2 a7 = sA2[7][j];
        float pr = a7.x, pi = a7.y;
#pragma unroll
        for (int m = 6; m >= 0; --m) {
            float2 a = sA2[m][j];
            pr = pr * t + a.x; pi = pi * t + a.y;
        }
        fr[7 - j] = pr; fi[7 - j] = pi;
    }
    fr[8] = 1.f; fi[8] = 0.f;

    // speed^2 / accel^2 via the precomputed real polys
    float sp2 = sSP2[12];
#pragma unroll
    for (int d = 11; d >= 0; --d) sp2 = sp2 * t + sSP2[d];
    sp2 = fmaxf(sp2, 0.f);
    float ac2 = sAC2[10];
#pragma unroll
    for (int d = 9; d >= 0; --d) ac2 = ac2 * t + sAC2[d];
    ac2 = fmaxf(ac2, 0.f);
    const float speed = sqrtf(sp2);

    // u_k = k * f_k  (g_j = f'_j = u_{j+1})
    float ur[9], uii[9];
#pragma unroll
    for (int k = 1; k < 9; ++k) { ur[k] = (float)k * fr[k]; uii[k] = (float)k * fi[k]; }

    // Bezout matrix B (8x8 complex symmetric): |det B| = |Res(f,f')| (f monic).
    // B[7][j] = u_{j+1} ; B[i-1][j] = c_{ij} + B[i][j-1], c computed lazily:
    // pair (a,b), a<b born at step i=b, last used at step i=a.
    float Br[8][8], Bi[8][8];
    float cRr[8][8], cIi[8][8];
#pragma unroll
    for (int j = 0; j < 8; ++j) { Br[7][j] = ur[j + 1]; Bi[7][j] = uii[j + 1]; }
#pragma unroll
    for (int i = 7; i >= 1; --i) {
#pragma unroll
        for (int j = 0; j < i; ++j) {   // fresh pairs (j, i)
            cRr[j][i] = (fr[j] * ur[i + 1] - fi[j] * uii[i + 1]) - (fr[i] * ur[j + 1] - fi[i] * uii[j + 1]);
            cIi[j][i] = (fr[j] * uii[i + 1] + fi[j] * ur[i + 1]) - (fr[i] * uii[j + 1] + fi[i] * ur[j + 1]);
        }
#pragma unroll
        for (int j = 0; j < 8; ++j) {
            float cr, ci;
            if (i < j)      { cr = cRr[i][j];  ci = cIi[i][j]; }
            else if (i > j) { cr = -cRr[j][i]; ci = -cIi[j][i]; }
            else            { cr = 0.f;        ci = 0.f; }
            if (j >= 1) { cr += Br[i][j - 1]; ci += Bi[i][j - 1]; }
            Br[i - 1][j] = cr; Bi[i - 1][j] = ci;
        }
    }

    // Pivot-free complex-symmetric LDL^T on the upper triangle (R5-identical).
    // log|det| via mantissa-product + exponent-sum.
    float logm = 1.f; int loge = 0;
#pragma unroll
    for (int k = 0; k < 8; ++k) {
        float dr = Br[k][k], di = Bi[k][k];
        float pm2 = dr * dr + di * di;
        unsigned ub = __float_as_uint(pm2);
        loge += (int)(ub >> 23) - 126;
        logm *= __uint_as_float((ub & 0x007fffffu) | 0x3f000000u);  // [0.5,1)
        if (k < 7) {
            float is = __builtin_amdgcn_rcpf(pm2);
            is = (pm2 > 1e-30f) ? is : 0.f;
            float ivr = dr * is, ivi = -di * is;          // 1/d
            float wr[8], wi[8];
#pragma unroll
            for (int i = k + 1; i < 8; ++i) {
                float ar = Br[k][i], ai = Bi[k][i];       // A[i][k] by symmetry
                wr[i] = ar * ivr - ai * ivi;
                wi[i] = ar * ivi + ai * ivr;
            }
#pragma unroll
            for (int i = k + 1; i < 8; ++i) {
#pragma unroll
                for (int j = i; j < 8; ++j) {
                    float br = Br[k][j], bi2 = Bi[k][j];
                    Br[i][j] -= wr[i] * br - wi[i] * bi2;
                    Bi[i][j] -= wr[i] * bi2 + wi[i] * br;
                }
            }
        }
    }
    float logdet = 0.5f * (__logf(logm) + (float)loge * 0.69314718055994531f);

    const float LOG_DISC_EPS = -27.63102111592855f;   // ln 1e-12
    const float LOG_DELTA2  = -27.63102111592855f;    // 2 ln 1e-6
    const float LOG1P_LEAD  = 1e-12f;                 // log(1 + 1e-12)
    float disc_logabs = logaddexp_f(logdet, LOG_DISC_EPS) - LOG1P_LEAD;
    float log_softabs = 0.5f * logaddexp_f(2.f * disc_logabs, LOG_DELTA2);
    float log_softabs_eps = logaddexp_f(log_softabs, LOG_DISC_EPS);
    float w = __expf(-log_softabs_eps * 0.125f);      // /N_DEG = /8

    float v1 = speed * w, v2 = sp2, v3 = ac2;
#pragma unroll
    for (int off = 32; off; off >>= 1) {
        v1 += __shfl_down(v1, off);
        v2 += __shfl_down(v2, off);
        v3 += __shfl_down(v3, off);
    }
    if (tid == 0) {
        partial[blockIdx.x * 3 + 0] = v1;
        partial[blockIdx.x * 3 + 1] = v2;
        partial[blockIdx.x * 3 + 2] = v3;
    }
}

__global__ __launch_bounds__(BLKF) void bez_finalize_kernel(
    const float* __restrict__ partial, float* __restrict__ out)
{
    const int tid = threadIdx.x;
    float v1 = 0.f, v2 = 0.f, v3 = 0.f;
#pragma unroll
    for (int k = 0; k < NBLK / BLKF; ++k) {
        const int b = tid + k * BLKF;
        v1 += partial[b * 3 + 0];
        v2 += partial[b * 3 + 1];
        v3 += partial[b * 3 + 2];
    }
#pragma unroll
    for (int off = 32; off; off >>= 1) {
        v1 += __shfl_down(v1, off);
        v2 += __shfl_down(v2, off);
        v3 += __shfl_down(v3, off);
    }
    __shared__ float red[4][3];
    const int wid = tid >> 6, lane = tid & 63;
    if (lane == 0) { red[wid][0] = v1; red[wid][1] = v2; red[wid][2] = v3; }
    __syncthreads();
    if (tid == 0) {
        float s1 = 0.f, s2 = 0.f, s3 = 0.f;
        for (int w2 = 0; w2 < 4; ++w2) { s1 += red[w2][0]; s2 += red[w2][1]; s3 += red[w2][2]; }
        const float Mf = (float)M_SAMPLES;
        out[0] = s1 / Mf + 0.1f * sqrtf(s2 / Mf) + 0.01f * sqrtf(s3 / Mf);
    }
}

extern "C" void kernel_launch(void* const* d_in, const int* in_sizes, int n_in,
                              void* d_out, int out_size, void* d_ws, size_t ws_size,
                              hipStream_t stream) {
    const float* P0   = (const float*)d_in[0];   // (8,2)
    const float* Pd   = (const float*)d_in[1];   // (8,2)
    const float* Pmid = (const float*)d_in[2];   // (6,8,2)
    const float* ts   = (const float*)d_in[3];   // (131072,)
    float* out = (float*)d_out;
    float* partial = (float*)d_ws;               // NBLK*3 floats (24 KB)

    bez_main_kernel<<<NBLK, BLK, 0, stream>>>(P0, Pd, Pmid, ts, partial);
    bez_finalize_kernel<<<1, BLKF, 0, stream>>>(partial, out);
}

// Round 8
// 14.977 us; speedup vs baseline: 1.1235x; 1.1235x over previous
//
#include <hip/hip_runtime.h>
#include <math.h>

#define M_SAMPLES 131072
#define BLK 256
#define NBLK (M_SAMPLES / BLK)   // 512

__device__ __forceinline__ float logaddexp_f(float a, float b) {
    float m = fmaxf(a, b);
    float d = fminf(a, b) - m;
    return m + __logf(1.f + __expf(d));
}

// C(m,k) table (rodata; runtime-indexed loads are memory, not registers)
__device__ const float BINOM[8][8] = {
  {1,0,0,0,0,0,0,0},{1,1,0,0,0,0,0,0},{1,2,1,0,0,0,0,0},{1,3,3,1,0,0,0,0},
  {1,4,6,4,1,0,0,0},{1,5,10,10,5,1,0,0},{1,6,15,20,15,6,1,0},{1,7,21,35,35,21,7,1}};

__global__ __launch_bounds__(BLK, 2) void bez_main_kernel(
    const float* __restrict__ P0, const float* __restrict__ Pd,
    const float* __restrict__ Pmid, const float* __restrict__ ts,
    float* __restrict__ partial)
{
    __shared__ float sP[8][8][2];
    __shared__ float2 sA2[8][8];    // monomial coeffs: T_j(t) = sum_m A[m][j] t^m
    __shared__ float sp1[13][8];    // per-(d,j) partials of |T'|^2 poly
    __shared__ float sp2p[11][8];   // per-(d,j) partials of |T''|^2 poly
    __shared__ float sSP2[13];      // sum_j |T'_j|^2 : real poly deg 12
    __shared__ float sAC2[11];      // sum_j |T''_j|^2: real poly deg 10
    __shared__ float red[4][3];

    const int tid = threadIdx.x;
    const int gid = blockIdx.x * BLK + tid;
    const float t = ts[gid];

    if (tid < 16) { sP[0][tid >> 1][tid & 1] = P0[tid]; sP[7][tid >> 1][tid & 1] = Pd[tid]; }
    if (tid < 96) { int r = tid / 16, rem = tid % 16; sP[1 + r][rem >> 1][rem & 1] = Pmid[tid]; }
    __syncthreads();
    // Bezier -> monomial: A_m = C(7,m) * sum_{k<=m} (-1)^(m-k) C(m,k) P_k
    if (tid < 64) {
        int m = tid >> 3, j = tid & 7;
        float aR = 0.f, aI = 0.f;
        float sgn = (m & 1) ? -1.f : 1.f;           // (-1)^m at k=0
        for (int k = 0; k <= m; ++k) {
            aR += sgn * BINOM[m][k] * sP[k][j][0];
            aI += sgn * BINOM[m][k] * sP[k][j][1];
            sgn = -sgn;
        }
        sA2[m][j] = make_float2(BINOM[7][m] * aR, BINOM[7][m] * aI);
    }
    __syncthreads();
    // Parallel partials: lane (d,j) sums over m — short, wide, no serial chain.
    if (tid < 104) {                                  // |T'|^2: d = 0..12
        int d = tid >> 3, j = tid & 7;
        int lo = d > 6 ? d - 6 : 0, hi = d < 6 ? d : 6;
        float s = 0.f;
        for (int m = lo; m <= hi; ++m) {
            int mp = d - m;
            float wgt = (float)((m + 1) * (mp + 1));
            float2 a = sA2[m + 1][j], b = sA2[mp + 1][j];
            s += wgt * (a.x * b.x + a.y * b.y);
        }
        sp1[d][j] = s;
    }
    if (tid >= 128 && tid < 216) {                    // |T''|^2: d = 0..10
        int d = (tid - 128) >> 3, j = (tid - 128) & 7;
        int lo = d > 5 ? d - 5 : 0, hi = d < 5 ? d : 5;
        float s = 0.f;
        for (int m = lo; m <= hi; ++m) {
            int mp = d - m;
            float wgt = (float)((m + 2) * (m + 1) * (mp + 2) * (mp + 1));
            float2 a = sA2[m + 2][j], b = sA2[mp + 2][j];
            s += wgt * (a.x * b.x + a.y * b.y);
        }
        sp2p[d][j] = s;
    }
    __syncthreads();
    if (tid < 13) {
        float s = 0.f;
        for (int j = 0; j < 8; ++j) s += sp1[tid][j];
        sSP2[tid] = s;
    }
    if (tid >= 64 && tid < 75) {
        float s = 0.f;
        for (int j = 0; j < 8; ++j) s += sp2p[tid - 64][j];
        sAC2[tid - 64] = s;
    }
    __syncthreads();

    // Per-thread: T_j via Horner (ascending storage f[7-j] = T_j), monic f_8 = 1.
    float fr[9], fi[9];
#pragma unroll
    for (int j = 0; j < 8; ++j) {
        float2 a7 = sA2[7][j];
        float pr = a7.x, pi = a7.y;
#pragma unroll
        for (int m = 6; m >= 0; --m) {
            float2 a = sA2[m][j];
            pr = pr * t + a.x; pi = pi * t + a.y;
        }
        fr[7 - j] = pr; fi[7 - j] = pi;
    }
    fr[8] = 1.f; fi[8] = 0.f;

    // speed^2 / accel^2 via the precomputed real polys
    float sp2 = sSP2[12];
#pragma unroll
    for (int d = 11; d >= 0; --d) sp2 = sp2 * t + sSP2[d];
    sp2 = fmaxf(sp2, 0.f);
    float ac2 = sAC2[10];
#pragma unroll
    for (int d = 9; d >= 0; --d) ac2 = ac2 * t + sAC2[d];
    ac2 = fmaxf(ac2, 0.f);
    const float speed = sqrtf(sp2);

    // u_k = k * f_k  (g_j = f'_j = u_{j+1})
    float ur[9], uii[9];
#pragma unroll
    for (int k = 1; k < 9; ++k) { ur[k] = (float)k * fr[k]; uii[k] = (float)k * fi[k]; }

    // Bezout matrix B (8x8 complex symmetric): |det B| = |Res(f,f')| (f monic).
    // B[7][j] = u_{j+1} ; B[i-1][j] = c_{ij} + B[i][j-1], c computed lazily.
    float Br[8][8], Bi[8][8];
    float cRr[8][8], cIi[8][8];
#pragma unroll
    for (int j = 0; j < 8; ++j) { Br[7][j] = ur[j + 1]; Bi[7][j] = uii[j + 1]; }
#pragma unroll
    for (int i = 7; i >= 1; --i) {
#pragma unroll
        for (int j = 0; j < i; ++j) {   // fresh pairs (j, i)
            cRr[j][i] = (fr[j] * ur[i + 1] - fi[j] * uii[i + 1]) - (fr[i] * ur[j + 1] - fi[i] * uii[j + 1]);
            cIi[j][i] = (fr[j] * uii[i + 1] + fi[j] * ur[i + 1]) - (fr[i] * uii[j + 1] + fi[i] * ur[j + 1]);
        }
#pragma unroll
        for (int j = 0; j < 8; ++j) {
            float cr, ci;
            if (i < j)      { cr = cRr[i][j];  ci = cIi[i][j]; }
            else if (i > j) { cr = -cRr[j][i]; ci = -cIi[j][i]; }
            else            { cr = 0.f;        ci = 0.f; }
            if (j >= 1) { cr += Br[i][j - 1]; ci += Bi[i][j - 1]; }
            Br[i - 1][j] = cr; Bi[i - 1][j] = ci;
        }
    }

    // Pivot-free complex-symmetric LDL^T on the upper triangle (R5-identical).
    // log|det| via mantissa-product + exponent-sum.
    float logm = 1.f; int loge = 0;
#pragma unroll
    for (int k = 0; k < 8; ++k) {
        float dr = Br[k][k], di = Bi[k][k];
        float pm2 = dr * dr + di * di;
        unsigned ub = __float_as_uint(pm2);
        loge += (int)(ub >> 23) - 126;
        logm *= __uint_as_float((ub & 0x007fffffu) | 0x3f000000u);  // [0.5,1)
        if (k < 7) {
            float is = __builtin_amdgcn_rcpf(pm2);
            is = (pm2 > 1e-30f) ? is : 0.f;
            float ivr = dr * is, ivi = -di * is;          // 1/d
            float wr[8], wi[8];
#pragma unroll
            for (int i = k + 1; i < 8; ++i) {
                float ar = Br[k][i], ai = Bi[k][i];       // A[i][k] by symmetry
                wr[i] = ar * ivr - ai * ivi;
                wi[i] = ar * ivi + ai * ivr;
            }
#pragma unroll
            for (int i = k + 1; i < 8; ++i) {
#pragma unroll
                for (int j = i; j < 8; ++j) {
                    float br = Br[k][j], bi2 = Bi[k][j];
                    Br[i][j] -= wr[i] * br - wi[i] * bi2;
                    Bi[i][j] -= wr[i] * bi2 + wi[i] * br;
                }
            }
        }
    }
    float logdet = 0.5f * (__logf(logm) + (float)loge * 0.69314718055994531f);

    const float LOG_DISC_EPS = -27.63102111592855f;   // ln 1e-12
    const float LOG_DELTA2  = -27.63102111592855f;    // 2 ln 1e-6
    const float LOG1P_LEAD  = 1e-12f;                 // log(1 + 1e-12)
    float disc_logabs = logaddexp_f(logdet, LOG_DISC_EPS) - LOG1P_LEAD;
    float log_softabs = 0.5f * logaddexp_f(2.f * disc_logabs, LOG_DELTA2);
    float log_softabs_eps = logaddexp_f(log_softabs, LOG_DISC_EPS);
    float w = __expf(-log_softabs_eps * 0.125f);      // /N_DEG = /8

    float v1 = speed * w, v2 = sp2, v3 = ac2;
#pragma unroll
    for (int off = 32; off; off >>= 1) {
        v1 += __shfl_down(v1, off);
        v2 += __shfl_down(v2, off);
        v3 += __shfl_down(v3, off);
    }
    const int wid = tid >> 6, lane = tid & 63;
    if (lane == 0) { red[wid][0] = v1; red[wid][1] = v2; red[wid][2] = v3; }
    __syncthreads();
    if (tid == 0) {
        float s1 = 0.f, s2 = 0.f, s3 = 0.f;
        for (int w2 = 0; w2 < 4; ++w2) { s1 += red[w2][0]; s2 += red[w2][1]; s3 += red[w2][2]; }
        partial[blockIdx.x * 3 + 0] = s1;
        partial[blockIdx.x * 3 + 1] = s2;
        partial[blockIdx.x * 3 + 2] = s3;
    }
}

__global__ __launch_bounds__(64) void bez_finalize_kernel(
    const float* __restrict__ partial, float* __restrict__ out)
{
    const int lane = threadIdx.x;
    float s1 = 0.f, s2 = 0.f, s3 = 0.f;
#pragma unroll
    for (int k = 0; k < NBLK / 64; ++k) {
        const int b = lane + k * 64;
        s1 += partial[b * 3 + 0];
        s2 += partial[b * 3 + 1];
        s3 += partial[b * 3 + 2];
    }
#pragma unroll
    for (int off = 32; off; off >>= 1) {
        s1 += __shfl_down(s1, off);
        s2 += __shfl_down(s2, off);
        s3 += __shfl_down(s3, off);
    }
    if (lane == 0) {
        const float Mf = (float)M_SAMPLES;
        out[0] = s1 / Mf + 0.1f * sqrtf(s2 / Mf) + 0.01f * sqrtf(s3 / Mf);
    }
}

extern "C" void kernel_launch(void* const* d_in, const int* in_sizes, int n_in,
                              void* d_out, int out_size, void* d_ws, size_t ws_size,
                              hipStream_t stream) {
    const float* P0   = (const float*)d_in[0];   // (8,2)
    const float* Pd   = (const float*)d_in[1];   // (8,2)
    const float* Pmid = (const float*)d_in[2];   // (6,8,2)
    const float* ts   = (const float*)d_in[3];   // (131072,)
    float* out = (float*)d_out;
    float* partial = (float*)d_ws;               // NBLK*3 floats

    bez_main_kernel<<<NBLK, BLK, 0, stream>>>(P0, Pd, Pmid, ts, partial);
    bez_finalize_kernel<<<1, 64, 0, stream>>>(partial, out);
}

// Round 9
// 14.267 us; speedup vs baseline: 1.1795x; 1.0498x over previous
//
#include <hip/hip_runtime.h>
#include <math.h>

#define M_SAMPLES 131072
#define BLK 256
#define NBLK (M_SAMPLES / (BLK * 2))   // 256 blocks, 2 samples/thread

__device__ __forceinline__ float logaddexp_f(float a, float b) {
    float m = fmaxf(a, b);
    float d = fminf(a, b) - m;
    return m + __logf(1.f + __expf(d));
}

// C(m,k) table (rodata; runtime-indexed loads are memory, not registers)
__device__ const float BINOM[8][8] = {
  {1,0,0,0,0,0,0,0},{1,1,0,0,0,0,0,0},{1,2,1,0,0,0,0,0},{1,3,3,1,0,0,0,0},
  {1,4,6,4,1,0,0,0},{1,5,10,10,5,1,0,0},{1,6,15,20,15,6,1,0},{1,7,21,35,35,21,7,1}};

// Full per-sample pipeline: Horner -> Bezout -> LDL -> weights.
// Returns (speed*w, sp2, ac2). All arrays statically indexed (no scratch).
__device__ __forceinline__ float3 eval_sample(
    float t, const float2 (*sA2)[8],
    const float* __restrict__ sSP2, const float* __restrict__ sAC2)
{
    // T_j via Horner (ascending storage f[7-j] = T_j), monic f_8 = 1.
    float fr[9], fi[9];
#pragma unroll
    for (int j = 0; j < 8; ++j) {
        float2 a7 = sA2[7][j];
        float pr = a7.x, pi = a7.y;
#pragma unroll
        for (int m = 6; m >= 0; --m) {
            float2 a = sA2[m][j];
            pr = pr * t + a.x; pi = pi * t + a.y;
        }
        fr[7 - j] = pr; fi[7 - j] = pi;
    }
    fr[8] = 1.f; fi[8] = 0.f;

    // speed^2 / accel^2 via the precomputed real polys
    float sp2 = sSP2[12];
#pragma unroll
    for (int d = 11; d >= 0; --d) sp2 = sp2 * t + sSP2[d];
    sp2 = fmaxf(sp2, 0.f);
    float ac2 = sAC2[10];
#pragma unroll
    for (int d = 9; d >= 0; --d) ac2 = ac2 * t + sAC2[d];
    ac2 = fmaxf(ac2, 0.f);
    const float speed = sqrtf(sp2);

    // u_k = k * f_k  (g_j = f'_j = u_{j+1})
    float ur[9], uii[9];
#pragma unroll
    for (int k = 1; k < 9; ++k) { ur[k] = (float)k * fr[k]; uii[k] = (float)k * fi[k]; }

    // Bezout matrix B (8x8 complex symmetric): |det B| = |Res(f,f')| (f monic).
    // B[7][j] = u_{j+1} ; B[i-1][j] = c_{ij} + B[i][j-1], c computed lazily.
    float Br[8][8], Bi[8][8];
    float cRr[8][8], cIi[8][8];
#pragma unroll
    for (int j = 0; j < 8; ++j) { Br[7][j] = ur[j + 1]; Bi[7][j] = uii[j + 1]; }
#pragma unroll
    for (int i = 7; i >= 1; --i) {
#pragma unroll
        for (int j = 0; j < i; ++j) {   // fresh pairs (j, i)
            cRr[j][i] = (fr[j] * ur[i + 1] - fi[j] * uii[i + 1]) - (fr[i] * ur[j + 1] - fi[i] * uii[j + 1]);
            cIi[j][i] = (fr[j] * uii[i + 1] + fi[j] * ur[i + 1]) - (fr[i] * uii[j + 1] + fi[i] * ur[j + 1]);
        }
#pragma unroll
        for (int j = 0; j < 8; ++j) {
            float cr, ci;
            if (i < j)      { cr = cRr[i][j];  ci = cIi[i][j]; }
            else if (i > j) { cr = -cRr[j][i]; ci = -cIi[j][i]; }
            else            { cr = 0.f;        ci = 0.f; }
            if (j >= 1) { cr += Br[i][j - 1]; ci += Bi[i][j - 1]; }
            Br[i - 1][j] = cr; Bi[i - 1][j] = ci;
        }
    }

    // Pivot-free complex-symmetric LDL^T on the upper triangle (R5-identical).
    // log|det| via mantissa-product + exponent-sum.
    float logm = 1.f; int loge = 0;
#pragma unroll
    for (int k = 0; k < 8; ++k) {
        float dr = Br[k][k], di = Bi[k][k];
        float pm2 = dr * dr + di * di;
        unsigned ub = __float_as_uint(pm2);
        loge += (int)(ub >> 23) - 126;
        logm *= __uint_as_float((ub & 0x007fffffu) | 0x3f000000u);  // [0.5,1)
        if (k < 7) {
            float is = __builtin_amdgcn_rcpf(pm2);
            is = (pm2 > 1e-30f) ? is : 0.f;
            float ivr = dr * is, ivi = -di * is;          // 1/d
            float wr[8], wi[8];
#pragma unroll
            for (int i = k + 1; i < 8; ++i) {
                float ar = Br[k][i], ai = Bi[k][i];       // A[i][k] by symmetry
                wr[i] = ar * ivr - ai * ivi;
                wi[i] = ar * ivi + ai * ivr;
            }
#pragma unroll
            for (int i = k + 1; i < 8; ++i) {
#pragma unroll
                for (int j = i; j < 8; ++j) {
                    float br = Br[k][j], bi2 = Bi[k][j];
                    Br[i][j] -= wr[i] * br - wi[i] * bi2;
                    Bi[i][j] -= wr[i] * bi2 + wi[i] * br;
                }
            }
        }
    }
    float logdet = 0.5f * (__logf(logm) + (float)loge * 0.69314718055994531f);

    const float LOG_DISC_EPS = -27.63102111592855f;   // ln 1e-12
    const float LOG_DELTA2  = -27.63102111592855f;    // 2 ln 1e-6
    const float LOG1P_LEAD  = 1e-12f;                 // log(1 + 1e-12)
    float disc_logabs = logaddexp_f(logdet, LOG_DISC_EPS) - LOG1P_LEAD;
    float log_softabs = 0.5f * logaddexp_f(2.f * disc_logabs, LOG_DELTA2);
    float log_softabs_eps = logaddexp_f(log_softabs, LOG_DISC_EPS);
    float w = __expf(-log_softabs_eps * 0.125f);      // /N_DEG = /8

    return make_float3(speed * w, sp2, ac2);
}

__global__ __launch_bounds__(BLK, 1) void bez_main_kernel(
    const float* __restrict__ P0, const float* __restrict__ Pd,
    const float* __restrict__ Pmid, const float* __restrict__ ts,
    float* __restrict__ partial)
{
    __shared__ float sP[8][8][2];
    __shared__ float2 sA2[8][8];    // monomial coeffs: T_j(t) = sum_m A[m][j] t^m
    __shared__ float sp1[13][8];    // per-(d,j) partials of |T'|^2 poly
    __shared__ float sp2p[11][8];   // per-(d,j) partials of |T''|^2 poly
    __shared__ float sSP2[13];      // sum_j |T'_j|^2 : real poly deg 12
    __shared__ float sAC2[11];      // sum_j |T''_j|^2: real poly deg 10
    __shared__ float red[4][3];

    const int tid = threadIdx.x;
    const int gidA = blockIdx.x * BLK + tid;
    const int gidB = gidA + (M_SAMPLES / 2);
    const float tA = ts[gidA];
    const float tB = ts[gidB];

    if (tid < 16) { sP[0][tid >> 1][tid & 1] = P0[tid]; sP[7][tid >> 1][tid & 1] = Pd[tid]; }
    if (tid < 96) { int r = tid / 16, rem = tid % 16; sP[1 + r][rem >> 1][rem & 1] = Pmid[tid]; }
    __syncthreads();
    // Bezier -> monomial: A_m = C(7,m) * sum_{k<=m} (-1)^(m-k) C(m,k) P_k
    if (tid < 64) {
        int m = tid >> 3, j = tid & 7;
        float aR = 0.f, aI = 0.f;
        float sgn = (m & 1) ? -1.f : 1.f;           // (-1)^m at k=0
        for (int k = 0; k <= m; ++k) {
            aR += sgn * BINOM[m][k] * sP[k][j][0];
            aI += sgn * BINOM[m][k] * sP[k][j][1];
            sgn = -sgn;
        }
        sA2[m][j] = make_float2(BINOM[7][m] * aR, BINOM[7][m] * aI);
    }
    __syncthreads();
    // Parallel partials: lane (d,j) sums over m — short, wide, no serial chain.
    if (tid < 104) {                                  // |T'|^2: d = 0..12
        int d = tid >> 3, j = tid & 7;
        int lo = d > 6 ? d - 6 : 0, hi = d < 6 ? d : 6;
        float s = 0.f;
        for (int m = lo; m <= hi; ++m) {
            int mp = d - m;
            float wgt = (float)((m + 1) * (mp + 1));
            float2 a = sA2[m + 1][j], b = sA2[mp + 1][j];
            s += wgt * (a.x * b.x + a.y * b.y);
        }
        sp1[d][j] = s;
    }
    if (tid >= 128 && tid < 216) {                    // |T''|^2: d = 0..10
        int d = (tid - 128) >> 3, j = (tid - 128) & 7;
        int lo = d > 5 ? d - 5 : 0, hi = d < 5 ? d : 5;
        float s = 0.f;
        for (int m = lo; m <= hi; ++m) {
            int mp = d - m;
            float wgt = (float)((m + 2) * (m + 1) * (mp + 2) * (mp + 1));
            float2 a = sA2[m + 2][j], b = sA2[mp + 2][j];
            s += wgt * (a.x * b.x + a.y * b.y);
        }
        sp2p[d][j] = s;
    }
    __syncthreads();
    if (tid < 13) {
        float s = 0.f;
        for (int j = 0; j < 8; ++j) s += sp1[tid][j];
        sSP2[tid] = s;
    }
    if (tid >= 64 && tid < 75) {
        float s = 0.f;
        for (int j = 0; j < 8; ++j) s += sp2p[tid - 64][j];
        sAC2[tid - 64] = s;
    }
    __syncthreads();

    // Two independent sample pipelines — compiler interleaves for ILP.
    float3 A = eval_sample(tA, sA2, sSP2, sAC2);
    float3 B = eval_sample(tB, sA2, sSP2, sAC2);

    float v1 = A.x + B.x, v2 = A.y + B.y, v3 = A.z + B.z;
#pragma unroll
    for (int off = 32; off; off >>= 1) {
        v1 += __shfl_down(v1, off);
        v2 += __shfl_down(v2, off);
        v3 += __shfl_down(v3, off);
    }
    const int wid = tid >> 6, lane = tid & 63;
    if (lane == 0) { red[wid][0] = v1; red[wid][1] = v2; red[wid][2] = v3; }
    __syncthreads();
    if (tid == 0) {
        float s1 = 0.f, s2 = 0.f, s3 = 0.f;
        for (int w2 = 0; w2 < 4; ++w2) { s1 += red[w2][0]; s2 += red[w2][1]; s3 += red[w2][2]; }
        partial[blockIdx.x * 3 + 0] = s1;
        partial[blockIdx.x * 3 + 1] = s2;
        partial[blockIdx.x * 3 + 2] = s3;
    }
}

__global__ __launch_bounds__(64) void bez_finalize_kernel(
    const float* __restrict__ partial, float* __restrict__ out)
{
    const int lane = threadIdx.x;
    float s1 = 0.f, s2 = 0.f, s3 = 0.f;
#pragma unroll
    for (int k = 0; k < NBLK / 64; ++k) {
        const int b = lane + k * 64;
        s1 += partial[b * 3 + 0];
        s2 += partial[b * 3 + 1];
        s3 += partial[b * 3 + 2];
    }
#pragma unroll
    for (int off = 32; off; off >>= 1) {
        s1 += __shfl_down(s1, off);
        s2 += __shfl_down(s2, off);
        s3 += __shfl_down(s3, off);
    }
    if (lane == 0) {
        const float Mf = (float)M_SAMPLES;
        out[0] = s1 / Mf + 0.1f * sqrtf(s2 / Mf) + 0.01f * sqrtf(s3 / Mf);
    }
}

extern "C" void kernel_launch(void* const* d_in, const int* in_sizes, int n_in,
                              void* d_out, int out_size, void* d_ws, size_t ws_size,
                              hipStream_t stream) {
    const float* P0   = (const float*)d_in[0];   // (8,2)
    const float* Pd   = (const float*)d_in[1];   // (8,2)
    const float* Pmid = (const float*)d_in[2];   // (6,8,2)
    const float* ts   = (const float*)d_in[3];   // (131072,)
    float* out = (float*)d_out;
    float* partial = (float*)d_ws;               // NBLK*3 floats

    bez_main_kernel<<<NBLK, BLK, 0, stream>>>(P0, Pd, Pmid, ts, partial);
    bez_finalize_kernel<<<1, 64, 0, stream>>>(partial, out);
}

// Round 10
// 12.934 us; speedup vs baseline: 1.3011x; 1.1031x over previous
//
#include <hip/hip_runtime.h>
#include <math.h>

#define M_SAMPLES 131072
#define BLK 256
#define NBLK (M_SAMPLES / (BLK * 2))   // 256 blocks, 2 samples/thread

typedef float v2f __attribute__((ext_vector_type(2)));

__device__ __forceinline__ v2f swapneg(v2f b) { return (v2f){-b.y, b.x}; }

__device__ __forceinline__ float logaddexp_f(float a, float b) {
    float m = fmaxf(a, b);
    float d = fminf(a, b) - m;
    return m + __logf(1.f + __expf(d));
}

// C(m,k) table (rodata; runtime-indexed loads are memory, not registers)
__device__ const float BINOM[8][8] = {
  {1,0,0,0,0,0,0,0},{1,1,0,0,0,0,0,0},{1,2,1,0,0,0,0,0},{1,3,3,1,0,0,0,0},
  {1,4,6,4,1,0,0,0},{1,5,10,10,5,1,0,0},{1,6,15,20,15,6,1,0},{1,7,21,35,35,21,7,1}};

// Full per-sample pipeline, complex values as packed float2 (v_pk_* f32 ops):
// Horner -> Bezout -> LDL -> weights. All arrays statically indexed.
__device__ __forceinline__ float3 eval_sample(
    float t, const v2f (*sA2)[8], const v2f* __restrict__ sPA)
{
    // T_j via Horner (ascending storage f[7-j] = T_j), monic f_8 = 1.
    v2f f[9];
#pragma unroll
    for (int j = 0; j < 8; ++j) {
        v2f p = sA2[7][j];
#pragma unroll
        for (int m = 6; m >= 0; --m) p = p * t + sA2[m][j];
        f[7 - j] = p;
    }
    f[8] = (v2f){1.f, 0.f};

    // speed^2 / accel^2: one packed real Horner (x: |T'|^2 deg12, y: |T''|^2 deg10)
    v2f pa = sPA[12];
#pragma unroll
    for (int d = 11; d >= 0; --d) pa = pa * t + sPA[d];
    const float sp2 = fmaxf(pa.x, 0.f);
    const float ac2 = fmaxf(pa.y, 0.f);
    const float speed = sqrtf(sp2);

    // u_k = k * f_k  (g_j = f'_j = u_{j+1}); us = swapneg(u) for complex mul
    v2f u[9], us[9];
#pragma unroll
    for (int k = 1; k < 9; ++k) { u[k] = (float)k * f[k]; us[k] = swapneg(u[k]); }

    // Bezout matrix B (8x8 complex symmetric): |det B| = |Res(f,f')| (f monic).
    // B[7][j] = u_{j+1} ; B[i-1][j] = c_{ij} + B[i][j-1], c computed lazily.
    // c_{a,b} = f_a (x) u_{b+1} - f_b (x) u_{a+1}; a (x) b = a.x*b + a.y*swapneg(b)
    v2f B[8][8], c[8][8];
#pragma unroll
    for (int j = 0; j < 8; ++j) B[7][j] = u[j + 1];
#pragma unroll
    for (int i = 7; i >= 1; --i) {
#pragma unroll
        for (int j = 0; j < i; ++j) {   // fresh pairs (j, i)
            c[j][i] = (f[j].x * u[i + 1] + f[j].y * us[i + 1])
                    - (f[i].x * u[j + 1] + f[i].y * us[j + 1]);
        }
#pragma unroll
        for (int j = 0; j < 8; ++j) {
            v2f cr;
            if (i < j)      cr = c[i][j];
            else if (i > j) cr = -c[j][i];
            else            cr = (v2f){0.f, 0.f};
            if (j >= 1) cr += B[i][j - 1];
            B[i - 1][j] = cr;
        }
    }

    // Pivot-free complex-symmetric LDL^T, upper triangle (same op order as R5/R9).
    // log|det| via mantissa-product + exponent-sum.
    float logm = 1.f; int loge = 0;
#pragma unroll
    for (int k = 0; k < 8; ++k) {
        v2f d = B[k][k];
        float pm2 = d.x * d.x + d.y * d.y;
        unsigned ub = __float_as_uint(pm2);
        loge += (int)(ub >> 23) - 126;
        logm *= __uint_as_float((ub & 0x007fffffu) | 0x3f000000u);  // [0.5,1)
        if (k < 7) {
            float is = __builtin_amdgcn_rcpf(pm2);
            is = (pm2 > 1e-30f) ? is : 0.f;
            v2f iv = (v2f){d.x * is, -d.y * is};          // 1/d
            v2f ivs = swapneg(iv);
            v2f w[8], bs[8];
#pragma unroll
            for (int i = k + 1; i < 8; ++i) {
                v2f a = B[k][i];                          // A[i][k] by symmetry
                w[i] = a.x * iv + a.y * ivs;              // w_i = a (x) 1/d
                bs[i] = swapneg(a);                       // reused across rows below
            }
#pragma unroll
            for (int i = k + 1; i < 8; ++i) {
#pragma unroll
                for (int j = i; j < 8; ++j) {
                    // B[i][j] -= w_i (x) B[k][j]
                    B[i][j] = B[i][j] - w[i].x * B[k][j] - w[i].y * bs[j];
                }
            }
        }
    }
    float logdet = 0.5f * (__logf(logm) + (float)loge * 0.69314718055994531f);

    const float LOG_DISC_EPS = -27.63102111592855f;   // ln 1e-12
    const float LOG_DELTA2  = -27.63102111592855f;    // 2 ln 1e-6
    const float LOG1P_LEAD  = 1e-12f;                 // log(1 + 1e-12)
    float disc_logabs = logaddexp_f(logdet, LOG_DISC_EPS) - LOG1P_LEAD;
    float log_softabs = 0.5f * logaddexp_f(2.f * disc_logabs, LOG_DELTA2);
    float log_softabs_eps = logaddexp_f(log_softabs, LOG_DISC_EPS);
    float w = __expf(-log_softabs_eps * 0.125f);      // /N_DEG = /8

    return make_float3(speed * w, sp2, ac2);
}

__global__ __launch_bounds__(BLK, 1) void bez_main_kernel(
    const float* __restrict__ P0, const float* __restrict__ Pd,
    const float* __restrict__ Pmid, const float* __restrict__ ts,
    float* __restrict__ partial)
{
    __shared__ float sP[8][8][2];
    __shared__ v2f sA2[8][8];       // monomial coeffs: T_j(t) = sum_m A[m][j] t^m
    __shared__ float sp1[13][8];    // per-(d,j) partials of |T'|^2 poly
    __shared__ float sp2p[11][8];   // per-(d,j) partials of |T''|^2 poly
    __shared__ v2f sPA[13];         // packed (|T'|^2 coeff, |T''|^2 coeff)
    __shared__ float red[4][3];

    const int tid = threadIdx.x;
    const int gidA = blockIdx.x * BLK + tid;
    const int gidB = gidA + (M_SAMPLES / 2);
    const float tA = ts[gidA];
    const float tB = ts[gidB];

    if (tid < 16) { sP[0][tid >> 1][tid & 1] = P0[tid]; sP[7][tid >> 1][tid & 1] = Pd[tid]; }
    if (tid < 96) { int r = tid / 16, rem = tid % 16; sP[1 + r][rem >> 1][rem & 1] = Pmid[tid]; }
    __syncthreads();
    // Bezier -> monomial: A_m = C(7,m) * sum_{k<=m} (-1)^(m-k) C(m,k) P_k
    if (tid < 64) {
        int m = tid >> 3, j = tid & 7;
        float aR = 0.f, aI = 0.f;
        float sgn = (m & 1) ? -1.f : 1.f;           // (-1)^m at k=0
        for (int k = 0; k <= m; ++k) {
            aR += sgn * BINOM[m][k] * sP[k][j][0];
            aI += sgn * BINOM[m][k] * sP[k][j][1];
            sgn = -sgn;
        }
        sA2[m][j] = (v2f){BINOM[7][m] * aR, BINOM[7][m] * aI};
    }
    __syncthreads();
    // Parallel partials: lane (d,j) sums over m — short, wide, no serial chain.
    if (tid < 104) {                                  // |T'|^2: d = 0..12
        int d = tid >> 3, j = tid & 7;
        int lo = d > 6 ? d - 6 : 0, hi = d < 6 ? d : 6;
        float s = 0.f;
        for (int m = lo; m <= hi; ++m) {
            int mp = d - m;
            float wgt = (float)((m + 1) * (mp + 1));
            v2f a = sA2[m + 1][j], b = sA2[mp + 1][j];
            s += wgt * (a.x * b.x + a.y * b.y);
        }
        sp1[d][j] = s;
    }
    if (tid >= 128 && tid < 216) {                    // |T''|^2: d = 0..10
        int d = (tid - 128) >> 3, j = (tid - 128) & 7;
        int lo = d > 5 ? d - 5 : 0, hi = d < 5 ? d : 5;
        float s = 0.f;
        for (int m = lo; m <= hi; ++m) {
            int mp = d - m;
            float wgt = (float)((m + 2) * (m + 1) * (mp + 2) * (mp + 1));
            v2f a = sA2[m + 2][j], b = sA2[mp + 2][j];
            s += wgt * (a.x * b.x + a.y * b.y);
        }
        sp2p[d][j] = s;
    }
    __syncthreads();
    if (tid < 13) {
        float s1 = 0.f, s2 = 0.f;
        for (int j = 0; j < 8; ++j) s1 += sp1[tid][j];
        if (tid <= 10) { for (int j = 0; j < 8; ++j) s2 += sp2p[tid][j]; }
        sPA[tid] = (v2f){s1, s2};
    }
    __syncthreads();

    // Two independent sample pipelines — compiler interleaves for ILP.
    float3 A = eval_sample(tA, sA2, sPA);
    float3 Bv = eval_sample(tB, sA2, sPA);

    float v1 = A.x + Bv.x, v2 = A.y + Bv.y, v3 = A.z + Bv.z;
#pragma unroll
    for (int off = 32; off; off >>= 1) {
        v1 += __shfl_down(v1, off);
        v2 += __shfl_down(v2, off);
        v3 += __shfl_down(v3, off);
    }
    const int wid = tid >> 6, lane = tid & 63;
    if (lane == 0) { red[wid][0] = v1; red[wid][1] = v2; red[wid][2] = v3; }
    __syncthreads();
    if (tid == 0) {
        float s1 = 0.f, s2 = 0.f, s3 = 0.f;
        for (int w2 = 0; w2 < 4; ++w2) { s1 += red[w2][0]; s2 += red[w2][1]; s3 += red[w2][2]; }
        partial[blockIdx.x * 3 + 0] = s1;
        partial[blockIdx.x * 3 + 1] = s2;
        partial[blockIdx.x * 3 + 2] = s3;
    }
}

__global__ __launch_bounds__(64) void bez_finalize_kernel(
    const float* __restrict__ partial, float* __restrict__ out)
{
    const int lane = threadIdx.x;
    float s1 = 0.f, s2 = 0.f, s3 = 0.f;
#pragma unroll
    for (int k = 0; k < NBLK / 64; ++k) {
        const int b = lane + k * 64;
        s1 += partial[b * 3 + 0];
        s2 += partial[b * 3 + 1];
        s3 += partial[b * 3 + 2];
    }
#pragma unroll
    for (int off = 32; off; off >>= 1) {
        s1 += __shfl_down(s1, off);
        s2 += __shfl_down(s2, off);
        s3 += __shfl_down(s3, off);
    }
    if (lane == 0) {
        const float Mf = (float)M_SAMPLES;
        out[0] = s1 / Mf + 0.1f * sqrtf(s2 / Mf) + 0.01f * sqrtf(s3 / Mf);
    }
}

extern "C" void kernel_launch(void* const* d_in, const int* in_sizes, int n_in,
                              void* d_out, int out_size, void* d_ws, size_t ws_size,
                              hipStream_t stream) {
    const float* P0   = (const float*)d_in[0];   // (8,2)
    const float* Pd   = (const float*)d_in[1];   // (8,2)
    const float* Pmid = (const float*)d_in[2];   // (6,8,2)
    const float* ts   = (const float*)d_in[3];   // (131072,)
    float* out = (float*)d_out;
    float* partial = (float*)d_ws;               // NBLK*3 floats

    bez_main_kernel<<<NBLK, BLK, 0, stream>>>(P0, Pd, Pmid, ts, partial);
    bez_finalize_kernel<<<1, 64, 0, stream>>>(partial, out);
}